// Round 3
// baseline (184.724 us; speedup 1.0000x reference)
//
#include <hip/hip_runtime.h>
#include <math.h>

#define NB 4
#define NC 256
#define NHEADS 4
#define DH 64
#define NT 4096            // 64*64 tokens per batch
// q pre-scale with log2(e) folded in: exp(s/8) == exp2(s * QSCALE)
#define QSCALE (0.125f * 1.44269504088896f)

typedef __bf16  bf16x8 __attribute__((ext_vector_type(8)));
typedef float   f32x4  __attribute__((ext_vector_type(4)));
typedef float   f32x16 __attribute__((ext_vector_type(16)));
typedef short   s16x8  __attribute__((ext_vector_type(8)));
typedef unsigned int u32x4 __attribute__((ext_vector_type(4)));

static __device__ __forceinline__ unsigned short f2bf(float f) {
    unsigned u = __float_as_uint(f);
    u = (u + 0x7fffu + ((u >> 16) & 1u)) >> 16;   // round-to-nearest-even
    return (unsigned short)u;
}

static __device__ __forceinline__ float fast_exp2(float x) {
    return __builtin_amdgcn_exp2f(x);
}

// pack two f32 -> one dword of 2 bf16 (RNE), single instruction
static __device__ __forceinline__ unsigned cvtpk(float lo, float hi) {
    unsigned r;
    asm("v_cvt_pk_bf16_f32 %0, %1, %2" : "=v"(r) : "v"(lo), "v"(hi));
    return r;
}

// half-wave swap: a' = {a_lo, b_lo}, b' = {a_hi, b_hi} (lanes 0-31 / 32-63)
static __device__ __forceinline__ void plswap(unsigned &a, unsigned &b) {
    asm("v_permlane32_swap_b32 %0, %1" : "+v"(a), "+v"(b));
}

static __device__ __forceinline__ bf16x8 as_bf16x8(u32x4 v) {
    return __builtin_bit_cast(bf16x8, v);
}

// async 16B/lane global -> LDS (DMA, no VGPR round-trip).
static __device__ __forceinline__ void gload16(const unsigned short* g, unsigned short* l) {
    __builtin_amdgcn_global_load_lds((const __attribute__((address_space(1))) void*)g,
                                     (__attribute__((address_space(3))) void*)l, 16, 0, 0);
}

// Stage 64 rows x 256 bf16 (global row stride 256 elems) -> LDS stride 264.
static __device__ __forceinline__ void stage_64x256(
    unsigned short* __restrict__ lds, const unsigned short* __restrict__ g, int tid)
{
    #pragma unroll
    for (int chunk = 0; chunk < 8; ++chunk) {
        const int row = chunk * 8 + (tid >> 5);
        const int col = (tid & 31) * 8;
        *(s16x8*)&lds[row * 264 + col] = *(const s16x8*)&g[row * 256 + col];
    }
}

// ---------------------------------------------------------------------------
// Kernel 0: weight prep (unchanged).
// ---------------------------------------------------------------------------
__global__ __launch_bounds__(256) void k_prep(
    const float* __restrict__ wqkv, const float* __restrict__ wproj,
    unsigned short* __restrict__ wqkv_t, unsigned short* __restrict__ wproj_bf)
{
    const int id = blockIdx.x;
    const int tid = threadIdx.x;
    if (id < 48) {
        __shared__ float T[64][65];
        const int jt = id % 12, ct = id / 12;
        #pragma unroll
        for (int p = 0; p < 16; ++p) {
            const int idx = tid + (p << 8);
            const int r = idx >> 6, cl = idx & 63;
            T[r][cl] = wqkv[(size_t)(ct * 64 + r) * 768 + jt * 64 + cl];
        }
        __syncthreads();
        #pragma unroll
        for (int p = 0; p < 16; ++p) {
            const int idx = tid + (p << 8);
            const int r = idx >> 6, cl = idx & 63;
            wqkv_t[(size_t)(jt * 64 + r) * 256 + ct * 64 + cl] = f2bf(T[cl][r]);
        }
    } else {
        const int base = (id - 48) * 2048 + tid * 8;
        s16x8 v;
        #pragma unroll
        for (int j = 0; j < 8; ++j) v[j] = (short)f2bf(wproj[base + j]);
        *(s16x8*)&wproj_bf[base] = v;
    }
}

// ---------------------------------------------------------------------------
// Kernel 1: LayerNorm + QKV GEMM via bf16 MFMA. (unchanged)
// ---------------------------------------------------------------------------
__global__ __launch_bounds__(256) void k_ln_qkv(
    const float* __restrict__ x,       // [B][C][N]
    const float* __restrict__ ln_g,
    const float* __restrict__ ln_b,
    const unsigned short* __restrict__ wqkv_t,  // [768][256] bf16
    unsigned short* __restrict__ q_bf,
    unsigned short* __restrict__ k_bf,
    unsigned short* __restrict__ v_bf)
{
    __shared__ unsigned short An[64 * 264];
    __shared__ unsigned short Wt[64 * 264];
    __shared__ float red1[4][64], red2[4][64];
    __shared__ float mu_s[64], rs_s[64];

    const int b     = blockIdx.x >> 6;
    const int n0    = (blockIdx.x & 63) << 6;
    const int three = blockIdx.y;
    const int tid   = threadIdx.x;
    const int li    = tid & 63;
    const int grp   = tid >> 6;
    const int w     = grp;
    const int lane  = li;
    const int q4    = lane >> 4;
    const int c     = lane & 15;

    const float* xb = x + ((size_t)b * NC) * NT + n0 + li;

    float xr[64];
    #pragma unroll
    for (int chunk = 0; chunk < 8; ++chunk)
        #pragma unroll
        for (int j = 0; j < 8; ++j)
            xr[chunk * 8 + j] = xb[(size_t)(chunk * 32 + grp * 8 + j) * NT];

    float s1 = 0.f, s2 = 0.f;
    #pragma unroll
    for (int i = 0; i < 64; ++i) { s1 += xr[i]; s2 += xr[i] * xr[i]; }
    red1[grp][li] = s1; red2[grp][li] = s2;
    __syncthreads();
    if (tid < 64) {
        const float t1 = red1[0][tid] + red1[1][tid] + red1[2][tid] + red1[3][tid];
        const float t2 = red2[0][tid] + red2[1][tid] + red2[2][tid] + red2[3][tid];
        const float mu  = t1 * (1.0f / NC);
        const float var = t2 * (1.0f / NC) - mu * mu;
        mu_s[tid] = mu;
        rs_s[tid] = rsqrtf(var + 1e-5f);
    }
    __syncthreads();
    const float mu = mu_s[li];
    const float rs = rs_s[li];

    #pragma unroll
    for (int chunk = 0; chunk < 8; ++chunk) {
        s16x8 pk;
        #pragma unroll
        for (int j = 0; j < 8; ++j) {
            const int ch = chunk * 32 + grp * 8 + j;
            const float vv = (xr[chunk * 8 + j] - mu) * rs * ln_g[ch] + ln_b[ch];
            pk[j] = (short)f2bf(vv);
        }
        *(s16x8*)&An[li * 264 + chunk * 32 + grp * 8] = pk;
    }
    __syncthreads();

    bf16x8 aT[8];
    if (three < 2) {
        #pragma unroll
        for (int kt = 0; kt < 8; ++kt)
            aT[kt] = *(const bf16x8*)&An[(16 * w + c) * 264 + kt * 32 + q4 * 8];
    }

    for (int jt = 0; jt < 4; ++jt) {
        __syncthreads();
        stage_64x256(Wt, wqkv_t + (size_t)(three * 256 + jt * 64) * 256, tid);
        __syncthreads();

        f32x4 acc[4];
        #pragma unroll
        for (int nt = 0; nt < 4; ++nt)
            #pragma unroll
            for (int r = 0; r < 4; ++r) acc[nt][r] = 0.f;

        const int bh = b * NHEADS + jt;
        if (three < 2) {
            #pragma unroll
            for (int nt = 0; nt < 4; ++nt)
                #pragma unroll
                for (int kt = 0; kt < 8; ++kt) {
                    const bf16x8 bb = *(const bf16x8*)&Wt[(16 * nt + c) * 264 + kt * 32 + q4 * 8];
                    acc[nt] = __builtin_amdgcn_mfma_f32_16x16x32_bf16(aT[kt], bb, acc[nt], 0, 0, 0);
                }
            unsigned short* dst = (three == 0 ? q_bf : k_bf) + ((size_t)bh * NT + n0) * DH;
            const float sc = (three == 0) ? QSCALE : 1.0f;
            #pragma unroll
            for (int nt = 0; nt < 4; ++nt)
                #pragma unroll
                for (int r = 0; r < 4; ++r)
                    dst[(size_t)(16 * w + 4 * q4 + r) * DH + 16 * nt + c] = f2bf(acc[nt][r] * sc);
        } else {
            bf16x8 aW[8];
            #pragma unroll
            for (int kt = 0; kt < 8; ++kt)
                aW[kt] = *(const bf16x8*)&Wt[(16 * w + c) * 264 + kt * 32 + q4 * 8];
            #pragma unroll
            for (int nt = 0; nt < 4; ++nt)
                #pragma unroll
                for (int kt = 0; kt < 8; ++kt) {
                    const bf16x8 bb = *(const bf16x8*)&An[(16 * nt + c) * 264 + kt * 32 + q4 * 8];
                    acc[nt] = __builtin_amdgcn_mfma_f32_16x16x32_bf16(aW[kt], bb, acc[nt], 0, 0, 0);
                }
            unsigned short* dst = v_bf + (size_t)bh * DH * NT;
            #pragma unroll
            for (int nt = 0; nt < 4; ++nt)
                #pragma unroll
                for (int r = 0; r < 4; ++r)
                    dst[(size_t)(16 * w + 4 * q4 + r) * NT + n0 + 16 * nt + c] = f2bf(acc[nt][r]);
        }
    }
}

// ---------------------------------------------------------------------------
// Kernel 2: NO-split-K flash attention, 32x32x16 MFMA, in-register softmax.
// R3 change: all FOUR 32-key sub-blocks' QK chains issued first (4 indep
// MFMA chains, dense issue), then a STAGGERED epilogue EXP(i)/PACK(i)/PV(i-1)
// so PV MFMA of sub-block i-1 overlaps exp-VALU of sub-block i WITHIN the
// wave (lockstep waves made cross-wave overlap the only prior source).
// S-tiles for 4 sub-blocks live simultaneously (+64 VGPR, free: LDS caps
// occupancy at 2 blocks/CU, VGPR cliff at 256).
// ---------------------------------------------------------------------------
__global__ __launch_bounds__(256, 2) void k_attn(
    const unsigned short* __restrict__ qg,  // [bh][n][d], pre-scaled by QSCALE
    const unsigned short* __restrict__ kg,  // [bh][n][d]
    const unsigned short* __restrict__ vg,  // [bh][d][n]  (transposed)
    unsigned short* __restrict__ og)        // [bh][n][d] bf16, normalized
{
    __shared__ unsigned short Ks[2 * 8192];   // 2 x (128 keys x 64 d)
    __shared__ unsigned short Vt[2 * 8192];   // 2 x (64 d x 128 keys)
    __shared__ float l_s[4][32];

    // bijective XCD swizzle: 512 = 8 XCD x 64; each XCD gets 2 contiguous bh.
    const int bx   = ((blockIdx.x & 7) << 6) | (blockIdx.x >> 3);
    const int bh   = bx >> 5;                  // 0..15
    const int qt   = bx & 31;                  // 0..31
    const int n0   = qt << 7;                  // 128-query tile base
    const int tid  = threadIdx.x;
    const int w    = tid >> 6;                 // wave -> queries qb..qb+31
    const int lane = tid & 63;
    const int c5   = lane & 31;
    const int hi   = lane >> 5;
    const int qb   = n0 + (w << 5);
    const int swz  = c5 & 7;

    const unsigned short* kb = kg + (size_t)bh * NT * DH;
    const unsigned short* vb = vg + (size_t)bh * DH * NT;

    // ---- Q frags direct from global: B-operand, lane(c5,hi) holds
    //      Q[query=qb+c5][d = 16ks + 8hi + e] ----
    bf16x8 aq[4];
    {
        const unsigned short* qrow = qg + ((size_t)bh * NT + qb + c5) * DH + hi * 8;
        #pragma unroll
        for (int ks = 0; ks < 4; ++ks)
            aq[ks] = *(const bf16x8*)(qrow + ks * 16);
    }

    // ---- staging lane geometry (per 1KB DMA instruction) ----
    // K tile rows = keys (128B each): 8 rows per 1KB group.
    const int rr  = lane >> 3;                 // row within 8-row group
    const int kcK = (lane & 7) ^ rr;           // swizzled 16B chunk (K)
    // V tile rows = d (256B each): 4 rows per 1KB group.
    const int rd  = lane >> 4;                 // d-row within 4-row group
    const int ckV = lane & 15;                 // 16B chunk within 256B row

    #define ISSUE_TILE(it_, bi_)                                               \
        {                                                                      \
            const unsigned short* ktp = kb + (size_t)(it_) * 128 * DH;         \
            const unsigned short* vtp = vb + (size_t)(it_) * 128;              \
            _Pragma("unroll")                                                  \
            for (int t = 0; t < 4; ++t) {                                      \
                const int grp_ = w * 4 + t;                                    \
                gload16(ktp + (size_t)(grp_ * 8 + rr) * DH + kcK * 8,          \
                        &Ks[(bi_) * 8192 + grp_ * 512 + lane * 8]);            \
                const int kcV_ = ckV ^ ((4 * grp_ + rd) & 7);                  \
                gload16(vtp + (size_t)(4 * grp_ + rd) * NT + kcV_ * 8,         \
                        &Vt[(bi_) * 8192 + grp_ * 512 + lane * 8]);            \
            }                                                                  \
        }

    // ---- per-sub-block phase macros (all loops compile-time unrolled) ----
    #define QK_SB(sv, sb)                                                      \
        {                                                                      \
            _Pragma("unroll")                                                  \
            for (int ks = 0; ks < 4; ++ks) {                                   \
                const bf16x8 kf = *(const bf16x8*)                             \
                    &Kb[((sb) * 32 + c5) * 64 + (((2 * ks + hi) ^ swz) << 3)]; \
                sv = __builtin_amdgcn_mfma_f32_32x32x16_bf16(kf, aq[ks], sv, 0, 0, 0); \
            }                                                                  \
        }

    #define EXP_SB(sv)                                                         \
        {                                                                      \
            _Pragma("unroll")                                                  \
            for (int r = 0; r < 16; r += 4) {                                  \
                sv[r]   = fast_exp2(sv[r]);   ls0 += sv[r];                    \
                sv[r+1] = fast_exp2(sv[r+1]); ls1 += sv[r+1];                  \
                sv[r+2] = fast_exp2(sv[r+2]); ls2 += sv[r+2];                  \
                sv[r+3] = fast_exp2(sv[r+3]); ls3 += sv[r+3];                  \
            }                                                                  \
        }

    #define PACK_SB(sv, pa0, pa1)                                              \
        {                                                                      \
            unsigned x0 = cvtpk(sv[0], sv[1]),  x1 = cvtpk(sv[4], sv[5]);      \
            plswap(x0, x1);                                                    \
            unsigned x2 = cvtpk(sv[2], sv[3]),  x3 = cvtpk(sv[6], sv[7]);      \
            plswap(x2, x3);                                                    \
            pa0 = (u32x4){x0, x2, x1, x3};                                     \
            unsigned y0 = cvtpk(sv[8], sv[9]),  y1 = cvtpk(sv[12], sv[13]);    \
            plswap(y0, y1);                                                    \
            unsigned y2 = cvtpk(sv[10], sv[11]), y3 = cvtpk(sv[14], sv[15]);   \
            plswap(y2, y3);                                                    \
            pa1 = (u32x4){y0, y2, y1, y3};                                     \
        }

    #define PV_SB(pa0, pa1, sb)                                                \
        {                                                                      \
            _Pragma("unroll")                                                  \
            for (int dt = 0; dt < 2; ++dt) {                                   \
                const int rv = (dt * 32 + c5) * 128;                           \
                const bf16x8 vA = *(const bf16x8*)                             \
                    &Vb[rv + (((4 * (sb) + hi) ^ swz) << 3)];                  \
                oac[dt] = __builtin_amdgcn_mfma_f32_32x32x16_bf16(             \
                    as_bf16x8(pa0), vA, oac[dt], 0, 0, 0);                     \
                const bf16x8 vB = *(const bf16x8*)                             \
                    &Vb[rv + (((4 * (sb) + 2 + hi) ^ swz) << 3)];              \
                oac[dt] = __builtin_amdgcn_mfma_f32_32x32x16_bf16(             \
                    as_bf16x8(pa1), vB, oac[dt], 0, 0, 0);                     \
            }                                                                  \
        }

    ISSUE_TILE(0, 0)

    f32x16 oac[2];
    #pragma unroll
    for (int dt = 0; dt < 2; ++dt)
        #pragma unroll
        for (int r = 0; r < 16; ++r) oac[dt][r] = 0.f;
    float ls0 = 0.f, ls1 = 0.f, ls2 = 0.f, ls3 = 0.f;   // 4 partial l chains

    for (int it = 0; it < 32; ++it) {
        const int cur = it & 1;
        asm volatile("s_waitcnt vmcnt(0)\n\ts_barrier" ::: "memory");
        if (it < 31) ISSUE_TILE(it + 1, cur ^ 1)

        const unsigned short* Kb = &Ks[cur * 8192];
        const unsigned short* Vb = &Vt[cur * 8192];

        // ---- QK for all 4 sub-blocks: 16 MFMA, 4 independent chains ----
        f32x16 sA, sB, sC, sD;
        #pragma unroll
        for (int r = 0; r < 16; ++r) { sA[r] = 0.f; sB[r] = 0.f; sC[r] = 0.f; sD[r] = 0.f; }

        __builtin_amdgcn_s_setprio(1);
        QK_SB(sA, 0)
        QK_SB(sB, 1)
        QK_SB(sC, 2)
        QK_SB(sD, 3)
        __builtin_amdgcn_s_setprio(0);

        // ---- staggered epilogue: PV(i) MFMA overlaps EXP(i+1) VALU ----
        u32x4 a0, a1, b0, b1, c0, c1, d0, d1;
        EXP_SB(sA)
        PACK_SB(sA, a0, a1)
        EXP_SB(sB)
        PV_SB(a0, a1, 0)
        PACK_SB(sB, b0, b1)
        EXP_SB(sC)
        PV_SB(b0, b1, 1)
        PACK_SB(sC, c0, c1)
        EXP_SB(sD)
        PV_SB(c0, c1, 2)
        PACK_SB(sD, d0, d1)
        PV_SB(d0, d1, 3)
    }
    #undef ISSUE_TILE
    #undef QK_SB
    #undef EXP_SB
    #undef PACK_SB
    #undef PV_SB

    // ---- per-query l: query c5 owned by this wave; redistribute via LDS ----
    const float lsum = (ls0 + ls1) + (ls2 + ls3);
    const float t = lsum + __shfl_xor(lsum, 32);
    if (lane < 32) l_s[w][c5] = t;
    __syncthreads();

    // ---- normalize + write bf16 O: row r -> query (r&3)+8*(r>>2)+4*hi ----
    unsigned short* ob = og + ((size_t)bh * NT + qb) * DH;
    #pragma unroll
    for (int r = 0; r < 16; ++r) {
        const int qrow = (r & 3) + 8 * (r >> 2) + 4 * hi;
        const float rn = 1.0f / l_s[w][qrow];
        ob[(size_t)qrow * DH + c5]      = f2bf(oac[0][r] * rn);
        ob[(size_t)qrow * DH + 32 + c5] = f2bf(oac[1][r] * rn);
    }
}

// ---------------------------------------------------------------------------
// Kernel 3: output projection via bf16 MFMA. O arrives normalized bf16 ->
// staging is a straight 16B copy (no split-K combine, no f32 traffic).
// ---------------------------------------------------------------------------
__global__ __launch_bounds__(256) void k_proj(
    const unsigned short* __restrict__ o_bf,     // [bh][n][64] bf16 normalized
    const unsigned short* __restrict__ wproj_bf, // [256][256] bf16
    const float* __restrict__ b_proj,
    float* __restrict__ out)                     // [B][C][N]
{
    __shared__ unsigned short Os[64 * 264];
    __shared__ unsigned short Ws[64 * 264];

    const int b   = blockIdx.x >> 6;
    const int n0  = (blockIdx.x & 63) << 6;
    const int yh  = blockIdx.y;                  // 0..1 -> cg half
    const int tid = threadIdx.x;
    const int w   = tid >> 6;
    const int lane = tid & 63;
    const int q4  = lane >> 4;
    const int c   = lane & 15;

    // ---- stage O tile: [token][c = hd*64 + d] bf16, direct 16B copies ----
    #pragma unroll
    for (int chunk = 0; chunk < 8; ++chunk) {
        const int row = chunk * 8 + (tid >> 5);
        const int col = (tid & 31) * 8;
        const int hd  = col >> 6;
        const int c64 = col & 63;
        const unsigned short* src =
            &o_bf[((size_t)(b * NHEADS + hd) * NT + n0 + row) * DH + c64];
        *(s16x8*)&Os[row * 264 + col] = *(const s16x8*)src;
    }

    for (int ct = 0; ct < 2; ++ct) {
        const int cg0 = (yh * 2 + ct) * 64;
        if (ct) __syncthreads();                 // Ws reuse guard
        stage_64x256(Ws, wproj_bf + (size_t)cg0 * NC, tid);
        __syncthreads();                         // Ws (and on ct==0, Os) visible

        bf16x8 a[8];
        #pragma unroll
        for (int kt = 0; kt < 8; ++kt)
            a[kt] = *(const bf16x8*)&Ws[(16 * w + c) * 264 + kt * 32 + q4 * 8];

        f32x4 acc[4];
        #pragma unroll
        for (int nt = 0; nt < 4; ++nt)
            #pragma unroll
            for (int r = 0; r < 4; ++r) acc[nt][r] = 0.f;

        #pragma unroll
        for (int nt = 0; nt < 4; ++nt)
            #pragma unroll
            for (int kt = 0; kt < 8; ++kt) {
                const bf16x8 bb = *(const bf16x8*)&Os[(16 * nt + c) * 264 + kt * 32 + q4 * 8];
                acc[nt] = __builtin_amdgcn_mfma_f32_16x16x32_bf16(a[kt], bb, acc[nt], 0, 0, 0);
            }

        #pragma unroll
        for (int nt = 0; nt < 4; ++nt)
            #pragma unroll
            for (int r = 0; r < 4; ++r) {
                const int cg = cg0 + 16 * w + 4 * q4 + r;
                out[((size_t)b * NC + cg) * NT + n0 + 16 * nt + c] = acc[nt][r] + b_proj[cg];
            }
    }
}

// ---------------------------------------------------------------------------
extern "C" void kernel_launch(void* const* d_in, const int* in_sizes, int n_in,
                              void* d_out, int out_size, void* d_ws, size_t ws_size,
                              hipStream_t stream)
{
    const float* x      = (const float*)d_in[0];
    const float* ln_g   = (const float*)d_in[1];
    const float* ln_b   = (const float*)d_in[2];
    const float* w_qkv  = (const float*)d_in[3];
    const float* w_proj = (const float*)d_in[4];
    const float* b_proj = (const float*)d_in[5];
    float* out = (float*)d_out;

    const size_t TEN = (size_t)NB * NHEADS * NT * DH;   // 4,194,304 elements

    unsigned short* ws16 = (unsigned short*)d_ws;
    unsigned short* q_bf    = ws16;
    unsigned short* k_bf    = ws16 + TEN;
    unsigned short* v_bf    = ws16 + 2 * TEN;
    unsigned short* o_bf    = ws16 + 3 * TEN;
    unsigned short* wqkv_t  = ws16 + 4 * TEN;            // [768][256]
    unsigned short* wproj_b = wqkv_t + 768 * 256;        // [256][256]

    k_prep<<<80, 256, 0, stream>>>(w_qkv, w_proj, wqkv_t, wproj_b);
    k_ln_qkv<<<dim3(NB * 64, 3), 256, 0, stream>>>(x, ln_g, ln_b, wqkv_t, q_bf, k_bf, v_bf);
    k_attn<<<512, 256, 0, stream>>>(q_bf, k_bf, v_bf, o_bf);
    k_proj<<<dim3(NB * 64, 2), 256, 0, stream>>>(o_bf, wproj_b, b_proj, out);
}

// Round 6
// 182.853 us; speedup vs baseline: 1.0102x; 1.0102x over previous
//
#include <hip/hip_runtime.h>
#include <math.h>

#define NB 4
#define NC 256
#define NHEADS 4
#define DH 64
#define NT 4096            // 64*64 tokens per batch
// q pre-scale with log2(e) folded in: exp(s/8) == exp2(s * QSCALE)
#define QSCALE (0.125f * 1.44269504088896f)

typedef __bf16  bf16x8 __attribute__((ext_vector_type(8)));
typedef float   f32x4  __attribute__((ext_vector_type(4)));
typedef float   f32x16 __attribute__((ext_vector_type(16)));
typedef short   s16x8  __attribute__((ext_vector_type(8)));
typedef unsigned int u32x4 __attribute__((ext_vector_type(4)));

static __device__ __forceinline__ unsigned short f2bf(float f) {
    unsigned u = __float_as_uint(f);
    u = (u + 0x7fffu + ((u >> 16) & 1u)) >> 16;   // round-to-nearest-even
    return (unsigned short)u;
}

static __device__ __forceinline__ float fast_exp2(float x) {
    return __builtin_amdgcn_exp2f(x);
}

// pack two f32 -> one dword of 2 bf16 (RNE), single instruction
static __device__ __forceinline__ unsigned cvtpk(float lo, float hi) {
    unsigned r;
    asm("v_cvt_pk_bf16_f32 %0, %1, %2" : "=v"(r) : "v"(lo), "v"(hi));
    return r;
}

// half-wave swap: a' = {a_lo, b_lo}, b' = {a_hi, b_hi} (lanes 0-31 / 32-63)
static __device__ __forceinline__ void plswap(unsigned &a, unsigned &b) {
    asm("v_permlane32_swap_b32 %0, %1" : "+v"(a), "+v"(b));
}

static __device__ __forceinline__ bf16x8 as_bf16x8(u32x4 v) {
    return __builtin_bit_cast(bf16x8, v);
}

// async 16B/lane global -> LDS (DMA, no VGPR round-trip).
static __device__ __forceinline__ void gload16(const unsigned short* g, unsigned short* l) {
    __builtin_amdgcn_global_load_lds((const __attribute__((address_space(1))) void*)g,
                                     (__attribute__((address_space(3))) void*)l, 16, 0, 0);
}

// Stage 64 rows x 256 bf16 (global row stride 256 elems) -> LDS stride 264.
static __device__ __forceinline__ void stage_64x256(
    unsigned short* __restrict__ lds, const unsigned short* __restrict__ g, int tid)
{
    #pragma unroll
    for (int chunk = 0; chunk < 8; ++chunk) {
        const int row = chunk * 8 + (tid >> 5);
        const int col = (tid & 31) * 8;
        *(s16x8*)&lds[row * 264 + col] = *(const s16x8*)&g[row * 256 + col];
    }
}

// ---------------------------------------------------------------------------
// Kernel 0: weight prep (unchanged).
// ---------------------------------------------------------------------------
__global__ __launch_bounds__(256) void k_prep(
    const float* __restrict__ wqkv, const float* __restrict__ wproj,
    unsigned short* __restrict__ wqkv_t, unsigned short* __restrict__ wproj_bf)
{
    const int id = blockIdx.x;
    const int tid = threadIdx.x;
    if (id < 48) {
        __shared__ float T[64][65];
        const int jt = id % 12, ct = id / 12;
        #pragma unroll
        for (int p = 0; p < 16; ++p) {
            const int idx = tid + (p << 8);
            const int r = idx >> 6, cl = idx & 63;
            T[r][cl] = wqkv[(size_t)(ct * 64 + r) * 768 + jt * 64 + cl];
        }
        __syncthreads();
        #pragma unroll
        for (int p = 0; p < 16; ++p) {
            const int idx = tid + (p << 8);
            const int r = idx >> 6, cl = idx & 63;
            wqkv_t[(size_t)(jt * 64 + r) * 256 + ct * 64 + cl] = f2bf(T[cl][r]);
        }
    } else {
        const int base = (id - 48) * 2048 + tid * 8;
        s16x8 v;
        #pragma unroll
        for (int j = 0; j < 8; ++j) v[j] = (short)f2bf(wproj[base + j]);
        *(s16x8*)&wproj_bf[base] = v;
    }
}

// ---------------------------------------------------------------------------
// Kernel 1: LayerNorm + QKV GEMM via bf16 MFMA.
// R5 change: grid (256,3) -> 256. Each block computes LN ONCE (x read once,
// not 3x; ~33MB HBM + 2/3 of LN VALU saved) then loops three=0..2 internally
// over the same 12 weight-tile GEMMs. Inner body identical to before with
// `three` a loop variable instead of blockIdx.y.
// ---------------------------------------------------------------------------
__global__ __launch_bounds__(256) void k_ln_qkv(
    const float* __restrict__ x,       // [B][C][N]
    const float* __restrict__ ln_g,
    const float* __restrict__ ln_b,
    const unsigned short* __restrict__ wqkv_t,  // [768][256] bf16
    unsigned short* __restrict__ q_bf,
    unsigned short* __restrict__ k_bf,
    unsigned short* __restrict__ v_bf)
{
    __shared__ unsigned short An[64 * 264];
    __shared__ unsigned short Wt[64 * 264];
    __shared__ float red1[4][64], red2[4][64];
    __shared__ float mu_s[64], rs_s[64];

    const int b     = blockIdx.x >> 6;
    const int n0    = (blockIdx.x & 63) << 6;
    const int tid   = threadIdx.x;
    const int li    = tid & 63;
    const int grp   = tid >> 6;
    const int w     = grp;
    const int lane  = li;
    const int q4    = lane >> 4;
    const int c     = lane & 15;

    const float* xb = x + ((size_t)b * NC) * NT + n0 + li;

    float xr[64];
    #pragma unroll
    for (int chunk = 0; chunk < 8; ++chunk)
        #pragma unroll
        for (int j = 0; j < 8; ++j)
            xr[chunk * 8 + j] = xb[(size_t)(chunk * 32 + grp * 8 + j) * NT];

    float s1 = 0.f, s2 = 0.f;
    #pragma unroll
    for (int i = 0; i < 64; ++i) { s1 += xr[i]; s2 += xr[i] * xr[i]; }
    red1[grp][li] = s1; red2[grp][li] = s2;
    __syncthreads();
    if (tid < 64) {
        const float t1 = red1[0][tid] + red1[1][tid] + red1[2][tid] + red1[3][tid];
        const float t2 = red2[0][tid] + red2[1][tid] + red2[2][tid] + red2[3][tid];
        const float mu  = t1 * (1.0f / NC);
        const float var = t2 * (1.0f / NC) - mu * mu;
        mu_s[tid] = mu;
        rs_s[tid] = rsqrtf(var + 1e-5f);
    }
    __syncthreads();
    const float mu = mu_s[li];
    const float rs = rs_s[li];

    #pragma unroll
    for (int chunk = 0; chunk < 8; ++chunk) {
        s16x8 pk;
        #pragma unroll
        for (int j = 0; j < 8; ++j) {
            const int ch = chunk * 32 + grp * 8 + j;
            const float vv = (xr[chunk * 8 + j] - mu) * rs * ln_g[ch] + ln_b[ch];
            pk[j] = (short)f2bf(vv);
        }
        *(s16x8*)&An[li * 264 + chunk * 32 + grp * 8] = pk;
    }
    __syncthreads();

    bf16x8 aT[8];
    #pragma unroll
    for (int kt = 0; kt < 8; ++kt)
        aT[kt] = *(const bf16x8*)&An[(16 * w + c) * 264 + kt * 32 + q4 * 8];

    for (int three = 0; three < 3; ++three) {
        for (int jt = 0; jt < 4; ++jt) {
            __syncthreads();
            stage_64x256(Wt, wqkv_t + (size_t)(three * 256 + jt * 64) * 256, tid);
            __syncthreads();

            f32x4 acc[4];
            #pragma unroll
            for (int nt = 0; nt < 4; ++nt)
                #pragma unroll
                for (int r = 0; r < 4; ++r) acc[nt][r] = 0.f;

            const int bh = b * NHEADS + jt;
            if (three < 2) {
                #pragma unroll
                for (int nt = 0; nt < 4; ++nt)
                    #pragma unroll
                    for (int kt = 0; kt < 8; ++kt) {
                        const bf16x8 bb = *(const bf16x8*)&Wt[(16 * nt + c) * 264 + kt * 32 + q4 * 8];
                        acc[nt] = __builtin_amdgcn_mfma_f32_16x16x32_bf16(aT[kt], bb, acc[nt], 0, 0, 0);
                    }
                unsigned short* dst = (three == 0 ? q_bf : k_bf) + ((size_t)bh * NT + n0) * DH;
                const float sc = (three == 0) ? QSCALE : 1.0f;
                #pragma unroll
                for (int nt = 0; nt < 4; ++nt)
                    #pragma unroll
                    for (int r = 0; r < 4; ++r)
                        dst[(size_t)(16 * w + 4 * q4 + r) * DH + 16 * nt + c] = f2bf(acc[nt][r] * sc);
            } else {
                bf16x8 aW[8];
                #pragma unroll
                for (int kt = 0; kt < 8; ++kt)
                    aW[kt] = *(const bf16x8*)&Wt[(16 * w + c) * 264 + kt * 32 + q4 * 8];
                #pragma unroll
                for (int nt = 0; nt < 4; ++nt)
                    #pragma unroll
                    for (int kt = 0; kt < 8; ++kt) {
                        const bf16x8 bb = *(const bf16x8*)&An[(16 * nt + c) * 264 + kt * 32 + q4 * 8];
                        acc[nt] = __builtin_amdgcn_mfma_f32_16x16x32_bf16(aW[kt], bb, acc[nt], 0, 0, 0);
                    }
                unsigned short* dst = v_bf + (size_t)bh * DH * NT;
                #pragma unroll
                for (int nt = 0; nt < 4; ++nt)
                    #pragma unroll
                    for (int r = 0; r < 4; ++r)
                        dst[(size_t)(16 * w + 4 * q4 + r) * NT + n0 + 16 * nt + c] = f2bf(acc[nt][r]);
            }
        }
    }
}

// ---------------------------------------------------------------------------
// Kernel 2: NO-split-K flash attention, 32x32x16 MFMA, in-register softmax.
// (R3 passing version verbatim; R4's anti-phase dual schedule was racy,
// withdrawn.)
// ---------------------------------------------------------------------------
__global__ __launch_bounds__(256, 2) void k_attn(
    const unsigned short* __restrict__ qg,  // [bh][n][d], pre-scaled by QSCALE
    const unsigned short* __restrict__ kg,  // [bh][n][d]
    const unsigned short* __restrict__ vg,  // [bh][d][n]  (transposed)
    unsigned short* __restrict__ og)        // [bh][n][d] bf16, normalized
{
    __shared__ unsigned short Ks[2 * 8192];   // 2 x (128 keys x 64 d)
    __shared__ unsigned short Vt[2 * 8192];   // 2 x (64 d x 128 keys)
    __shared__ float l_s[4][32];

    // bijective XCD swizzle: 512 = 8 XCD x 64; each XCD gets 2 contiguous bh.
    const int bx   = ((blockIdx.x & 7) << 6) | (blockIdx.x >> 3);
    const int bh   = bx >> 5;                  // 0..15
    const int qt   = bx & 31;                  // 0..31
    const int n0   = qt << 7;                  // 128-query tile base
    const int tid  = threadIdx.x;
    const int w    = tid >> 6;                 // wave -> queries qb..qb+31
    const int lane = tid & 63;
    const int c5   = lane & 31;
    const int hi   = lane >> 5;
    const int qb   = n0 + (w << 5);
    const int swz  = c5 & 7;

    const unsigned short* kb = kg + (size_t)bh * NT * DH;
    const unsigned short* vb = vg + (size_t)bh * DH * NT;

    // ---- Q frags direct from global: B-operand, lane(c5,hi) holds
    //      Q[query=qb+c5][d = 16ks + 8hi + e] ----
    bf16x8 aq[4];
    {
        const unsigned short* qrow = qg + ((size_t)bh * NT + qb + c5) * DH + hi * 8;
        #pragma unroll
        for (int ks = 0; ks < 4; ++ks)
            aq[ks] = *(const bf16x8*)(qrow + ks * 16);
    }

    // ---- staging lane geometry (per 1KB DMA instruction) ----
    // K tile rows = keys (128B each): 8 rows per 1KB group.
    const int rr  = lane >> 3;                 // row within 8-row group
    const int kcK = (lane & 7) ^ rr;           // swizzled 16B chunk (K)
    // V tile rows = d (256B each): 4 rows per 1KB group.
    const int rd  = lane >> 4;                 // d-row within 4-row group
    const int ckV = lane & 15;                 // 16B chunk within 256B row

    #define ISSUE_TILE(it_, bi_)                                               \
        {                                                                      \
            const unsigned short* ktp = kb + (size_t)(it_) * 128 * DH;         \
            const unsigned short* vtp = vb + (size_t)(it_) * 128;              \
            _Pragma("unroll")                                                  \
            for (int t = 0; t < 4; ++t) {                                      \
                const int grp_ = w * 4 + t;                                    \
                gload16(ktp + (size_t)(grp_ * 8 + rr) * DH + kcK * 8,          \
                        &Ks[(bi_) * 8192 + grp_ * 512 + lane * 8]);            \
                const int kcV_ = ckV ^ ((4 * grp_ + rd) & 7);                  \
                gload16(vtp + (size_t)(4 * grp_ + rd) * NT + kcV_ * 8,         \
                        &Vt[(bi_) * 8192 + grp_ * 512 + lane * 8]);            \
            }                                                                  \
        }

    // ---- per-sub-block phase macros (all loops compile-time unrolled) ----
    #define QK_SB(sv, sb)                                                      \
        {                                                                      \
            _Pragma("unroll")                                                  \
            for (int ks = 0; ks < 4; ++ks) {                                   \
                const bf16x8 kf = *(const bf16x8*)                             \
                    &Kb[((sb) * 32 + c5) * 64 + (((2 * ks + hi) ^ swz) << 3)]; \
                sv = __builtin_amdgcn_mfma_f32_32x32x16_bf16(kf, aq[ks], sv, 0, 0, 0); \
            }                                                                  \
        }

    #define EXP_SB(sv)                                                         \
        {                                                                      \
            _Pragma("unroll")                                                  \
            for (int r = 0; r < 16; r += 4) {                                  \
                sv[r]   = fast_exp2(sv[r]);   ls0 += sv[r];                    \
                sv[r+1] = fast_exp2(sv[r+1]); ls1 += sv[r+1];                  \
                sv[r+2] = fast_exp2(sv[r+2]); ls2 += sv[r+2];                  \
                sv[r+3] = fast_exp2(sv[r+3]); ls3 += sv[r+3];                  \
            }                                                                  \
        }

    #define PACK_SB(sv, pa0, pa1)                                              \
        {                                                                      \
            unsigned x0 = cvtpk(sv[0], sv[1]),  x1 = cvtpk(sv[4], sv[5]);      \
            plswap(x0, x1);                                                    \
            unsigned x2 = cvtpk(sv[2], sv[3]),  x3 = cvtpk(sv[6], sv[7]);      \
            plswap(x2, x3);                                                    \
            pa0 = (u32x4){x0, x2, x1, x3};                                     \
            unsigned y0 = cvtpk(sv[8], sv[9]),  y1 = cvtpk(sv[12], sv[13]);    \
            plswap(y0, y1);                                                    \
            unsigned y2 = cvtpk(sv[10], sv[11]), y3 = cvtpk(sv[14], sv[15]);   \
            plswap(y2, y3);                                                    \
            pa1 = (u32x4){y0, y2, y1, y3};                                     \
        }

    #define PV_SB(pa0, pa1, sb)                                                \
        {                                                                      \
            _Pragma("unroll")                                                  \
            for (int dt = 0; dt < 2; ++dt) {                                   \
                const int rv = (dt * 32 + c5) * 128;                           \
                const bf16x8 vA = *(const bf16x8*)                             \
                    &Vb[rv + (((4 * (sb) + hi) ^ swz) << 3)];                  \
                oac[dt] = __builtin_amdgcn_mfma_f32_32x32x16_bf16(             \
                    as_bf16x8(pa0), vA, oac[dt], 0, 0, 0);                     \
                const bf16x8 vB = *(const bf16x8*)                             \
                    &Vb[rv + (((4 * (sb) + 2 + hi) ^ swz) << 3)];              \
                oac[dt] = __builtin_amdgcn_mfma_f32_32x32x16_bf16(             \
                    as_bf16x8(pa1), vB, oac[dt], 0, 0, 0);                     \
            }                                                                  \
        }

    ISSUE_TILE(0, 0)

    f32x16 oac[2];
    #pragma unroll
    for (int dt = 0; dt < 2; ++dt)
        #pragma unroll
        for (int r = 0; r < 16; ++r) oac[dt][r] = 0.f;
    float ls0 = 0.f, ls1 = 0.f, ls2 = 0.f, ls3 = 0.f;   // 4 partial l chains

    for (int it = 0; it < 32; ++it) {
        const int cur = it & 1;
        asm volatile("s_waitcnt vmcnt(0)\n\ts_barrier" ::: "memory");
        if (it < 31) ISSUE_TILE(it + 1, cur ^ 1)

        const unsigned short* Kb = &Ks[cur * 8192];
        const unsigned short* Vb = &Vt[cur * 8192];

        // ---- QK for all 4 sub-blocks: 16 MFMA, 4 independent chains ----
        f32x16 sA, sB, sC, sD;
        #pragma unroll
        for (int r = 0; r < 16; ++r) { sA[r] = 0.f; sB[r] = 0.f; sC[r] = 0.f; sD[r] = 0.f; }

        __builtin_amdgcn_s_setprio(1);
        QK_SB(sA, 0)
        QK_SB(sB, 1)
        QK_SB(sC, 2)
        QK_SB(sD, 3)
        __builtin_amdgcn_s_setprio(0);

        // ---- staggered epilogue: PV(i) MFMA overlaps EXP(i+1) VALU ----
        u32x4 a0, a1, b0, b1, c0, c1, d0, d1;
        EXP_SB(sA)
        PACK_SB(sA, a0, a1)
        EXP_SB(sB)
        PV_SB(a0, a1, 0)
        PACK_SB(sB, b0, b1)
        EXP_SB(sC)
        PV_SB(b0, b1, 1)
        PACK_SB(sC, c0, c1)
        EXP_SB(sD)
        PV_SB(c0, c1, 2)
        PACK_SB(sD, d0, d1)
        PV_SB(d0, d1, 3)
    }
    #undef ISSUE_TILE
    #undef QK_SB
    #undef EXP_SB
    #undef PACK_SB
    #undef PV_SB

    // ---- per-query l: query c5 owned by this wave; redistribute via LDS ----
    const float lsum = (ls0 + ls1) + (ls2 + ls3);
    const float t = lsum + __shfl_xor(lsum, 32);
    if (lane < 32) l_s[w][c5] = t;
    __syncthreads();

    // ---- normalize + write bf16 O: row r -> query (r&3)+8*(r>>2)+4*hi ----
    unsigned short* ob = og + ((size_t)bh * NT + qb) * DH;
    #pragma unroll
    for (int r = 0; r < 16; ++r) {
        const int qrow = (r & 3) + 8 * (r >> 2) + 4 * hi;
        const float rn = 1.0f / l_s[w][qrow];
        ob[(size_t)qrow * DH + c5]      = f2bf(oac[0][r] * rn);
        ob[(size_t)qrow * DH + 32 + c5] = f2bf(oac[1][r] * rn);
    }
}

// ---------------------------------------------------------------------------
// Kernel 3: output projection via bf16 MFMA. O arrives normalized bf16 ->
// staging is a straight 16B copy (no split-K combine, no f32 traffic).
// ---------------------------------------------------------------------------
__global__ __launch_bounds__(256) void k_proj(
    const unsigned short* __restrict__ o_bf,     // [bh][n][64] bf16 normalized
    const unsigned short* __restrict__ wproj_bf, // [256][256] bf16
    const float* __restrict__ b_proj,
    float* __restrict__ out)                     // [B][C][N]
{
    __shared__ unsigned short Os[64 * 264];
    __shared__ unsigned short Ws[64 * 264];

    const int b   = blockIdx.x >> 6;
    const int n0  = (blockIdx.x & 63) << 6;
    const int yh  = blockIdx.y;                  // 0..1 -> cg half
    const int tid = threadIdx.x;
    const int w   = tid >> 6;
    const int lane = tid & 63;
    const int q4  = lane >> 4;
    const int c   = lane & 15;

    // ---- stage O tile: [token][c = hd*64 + d] bf16, direct 16B copies ----
    #pragma unroll
    for (int chunk = 0; chunk < 8; ++chunk) {
        const int row = chunk * 8 + (tid >> 5);
        const int col = (tid & 31) * 8;
        const int hd  = col >> 6;
        const int c64 = col & 63;
        const unsigned short* src =
            &o_bf[((size_t)(b * NHEADS + hd) * NT + n0 + row) * DH + c64];
        *(s16x8*)&Os[row * 264 + col] = *(const s16x8*)src;
    }

    for (int ct = 0; ct < 2; ++ct) {
        const int cg0 = (yh * 2 + ct) * 64;
        if (ct) __syncthreads();                 // Ws reuse guard
        stage_64x256(Ws, wproj_bf + (size_t)cg0 * NC, tid);
        __syncthreads();                         // Ws (and on ct==0, Os) visible

        bf16x8 a[8];
        #pragma unroll
        for (int kt = 0; kt < 8; ++kt)
            a[kt] = *(const bf16x8*)&Ws[(16 * w + c) * 264 + kt * 32 + q4 * 8];

        f32x4 acc[4];
        #pragma unroll
        for (int nt = 0; nt < 4; ++nt)
            #pragma unroll
            for (int r = 0; r < 4; ++r) acc[nt][r] = 0.f;

        #pragma unroll
        for (int nt = 0; nt < 4; ++nt)
            #pragma unroll
            for (int kt = 0; kt < 8; ++kt) {
                const bf16x8 bb = *(const bf16x8*)&Os[(16 * nt + c) * 264 + kt * 32 + q4 * 8];
                acc[nt] = __builtin_amdgcn_mfma_f32_16x16x32_bf16(a[kt], bb, acc[nt], 0, 0, 0);
            }

        #pragma unroll
        for (int nt = 0; nt < 4; ++nt)
            #pragma unroll
            for (int r = 0; r < 4; ++r) {
                const int cg = cg0 + 16 * w + 4 * q4 + r;
                out[((size_t)b * NC + cg) * NT + n0 + 16 * nt + c] = acc[nt][r] + b_proj[cg];
            }
    }
}

// ---------------------------------------------------------------------------
extern "C" void kernel_launch(void* const* d_in, const int* in_sizes, int n_in,
                              void* d_out, int out_size, void* d_ws, size_t ws_size,
                              hipStream_t stream)
{
    const float* x      = (const float*)d_in[0];
    const float* ln_g   = (const float*)d_in[1];
    const float* ln_b   = (const float*)d_in[2];
    const float* w_qkv  = (const float*)d_in[3];
    const float* w_proj = (const float*)d_in[4];
    const float* b_proj = (const float*)d_in[5];
    float* out = (float*)d_out;

    const size_t TEN = (size_t)NB * NHEADS * NT * DH;   // 4,194,304 elements

    unsigned short* ws16 = (unsigned short*)d_ws;
    unsigned short* q_bf    = ws16;
    unsigned short* k_bf    = ws16 + TEN;
    unsigned short* v_bf    = ws16 + 2 * TEN;
    unsigned short* o_bf    = ws16 + 3 * TEN;
    unsigned short* wqkv_t  = ws16 + 4 * TEN;            // [768][256]
    unsigned short* wproj_b = wqkv_t + 768 * 256;        // [256][256]

    k_prep<<<80, 256, 0, stream>>>(w_qkv, w_proj, wqkv_t, wproj_b);
    k_ln_qkv<<<NB * 64, 256, 0, stream>>>(x, ln_g, ln_b, wqkv_t, q_bf, k_bf, v_bf);
    k_attn<<<512, 256, 0, stream>>>(q_bf, k_bf, v_bf, o_bf);
    k_proj<<<dim3(NB * 64, 2), 256, 0, stream>>>(o_bf, wproj_b, b_proj, out);
}